// Round 18
// baseline (66.756 us; speedup 1.0000x reference)
//
#include <hip/hip_runtime.h>
#include <hip/hip_bf16.h>
#include <stdint.h>

typedef __bf16 bf16_t;
typedef bf16_t bf16x8 __attribute__((ext_vector_type(8)));
typedef bf16_t bf16x4 __attribute__((ext_vector_type(4)));
typedef float  f32x4  __attribute__((ext_vector_type(4)));
typedef float  f32x16 __attribute__((ext_vector_type(16)));

constexpr int Bsz = 16, Tsz = 1024, Hn = 8, Dk = 64;
constexpr int QB  = 512;                 // q rows per block (16 warps x 32)
constexpr int KVB = 64;                  // kv rows per window
constexpr int NIT = Tsz / KVB;           // 16
constexpr int STRIDE_T = Hn * Dk;        // 512 floats between consecutive t
constexpr float QSCALE = 0.125f * 1.44269504f;   // 1/sqrt(64) * log2(e)

// Barrier that waits only on LDS ops (lgkmcnt); in-flight global loads
// (wave-private registers) cross it and get their natural vmcnt wait at
// the consuming cvt next window. No sched_barrier pins (m141 lesson).
__device__ __forceinline__ void lds_barrier() {
    asm volatile("s_waitcnt lgkmcnt(0)" ::: "memory");
    __builtin_amdgcn_s_barrier();
}

__global__ __launch_bounds__(1024, 4)
void fattn(const float* __restrict__ Q, const float* __restrict__ K,
           const float* __restrict__ V, float* __restrict__ O)
{
    // ---- bijective XCD-aware swizzle: 256 wgs, 8 XCDs, 32 contiguous per XCD ----
    const int orig = blockIdx.x;
    const int wg   = (orig & 7) * 32 + (orig >> 3);
    const int qt   = wg & 1;              // 2 q-blocks per head, adjacent -> same XCD
    const int bh   = wg >> 1;
    const int h    = bh & (Hn - 1);
    const int b    = bh >> 3;

    const int tid  = threadIdx.x;
    const int warp = tid >> 6;            // 0..15
    const int lane = tid & 63;
    const int l31  = lane & 31;
    const int hi   = lane >> 5;           // 0/1

    // double-buffered tiles (32 KB total)
    __shared__ alignas(16) bf16_t Kl[2][KVB * Dk];   // [kv][e], XOR-swizzled rows
    __shared__ alignas(16) bf16_t Vl[2][Dk * KVB];   // V^T: [d][pos], pos = swap23(kv), XOR-swizzled

    const size_t base = (size_t)b * (Tsz * Hn * Dk) + (size_t)h * Dk;
    const float* Qb = Q + base;
    const float* Kb = K + base;
    const float* Vb = V + base;
    float*       Ob = O + base;

    // ---- Q fragments (B operand of swapped QK^T), scale*log2e folded ----
    bf16x8 qf[4];
    {
        const float* qs = Qb + (size_t)(qt * QB + warp * 32 + l31) * STRIDE_T + hi * 8;
        #pragma unroll
        for (int ks = 0; ks < 4; ++ks) {
            f32x4 lo = *reinterpret_cast<const f32x4*>(qs + ks * 16);
            f32x4 hh = *reinterpret_cast<const f32x4*>(qs + ks * 16 + 4);
            bf16x8 f;
            #pragma unroll
            for (int j = 0; j < 4; ++j) {
                f[j]     = (bf16_t)(lo[j] * QSCALE);
                f[4 + j] = (bf16_t)(hh[j] * QSCALE);
            }
            qf[ks] = f;
        }
    }

    // ---- staging assignments (1024 threads; 4 elems each for K and V) ----
    const int kr  = tid >> 4;             // 0..63
    const int ke0 = (tid & 15) * 4;       // 0..60
    const float* kg = Kb + (size_t)kr * STRIDE_T + ke0;
    const uint32_t kidx = (uint32_t)(kr * Dk + ke0) ^ (uint32_t)((kr & 7) << 3);

    const int vd   = tid & 63;
    const int pos0 = (tid >> 6) * 4;      // 0..60 (multiple of 4)
    const int vs0  = (pos0 & ~12) | ((pos0 & 4) << 1) | ((pos0 & 8) >> 1);   // swap23
    const float* vgp = Vb + (size_t)vs0 * STRIDE_T + vd;
    const uint32_t vidx = (uint32_t)(vd * KVB + pos0) ^ (uint32_t)((vd & 7) << 3);

    const uint32_t swz = (uint32_t)((l31 & 7) << 3);

    // ---- accumulators; l per-lane-half, merged in epilogue ----
    f32x16 o0, o1;
    #pragma unroll
    for (int r = 0; r < 16; ++r) { o0[r] = 0.f; o1[r] = 0.f; }
    float l_acc = 0.f;

    // ---- prologue: load t0 -> write buf0 -> load t1 -> barrier ----
    f32x4 kra;
    float vv[4];
    kra = *reinterpret_cast<const f32x4*>(kg);
    #pragma unroll
    for (int j = 0; j < 4; ++j) vv[j] = vgp[(size_t)j * STRIDE_T];
    {
        bf16x4 kw;
        #pragma unroll
        for (int j = 0; j < 4; ++j) kw[j] = (bf16_t)kra[j];
        *reinterpret_cast<bf16x4*>(&Kl[0][kidx]) = kw;
        bf16x4 vw;
        #pragma unroll
        for (int j = 0; j < 4; ++j) vw[j] = (bf16_t)vv[j];
        *reinterpret_cast<bf16x4*>(&Vl[0][vidx]) = vw;
    }
    kg  += (size_t)KVB * STRIDE_T;
    vgp += (size_t)KVB * STRIDE_T;
    kra = *reinterpret_cast<const f32x4*>(kg);
    #pragma unroll
    for (int j = 0; j < 4; ++j) vv[j] = vgp[(size_t)j * STRIDE_T];
    lds_barrier();

    for (int t = 0; t < NIT; ++t) {
        const int cur = t & 1;

        // ---- window top (post-barrier): write tile t+1 into buf[cur^1].
        //      The cvts below carry the natural vmcnt wait for loads issued
        //      mid window t-1 (~1.5 windows of flight). These ds_writes
        //      overlap this window's QK MFMAs. ----
        if (t + 1 < NIT) {
            bf16x4 kw;
            #pragma unroll
            for (int j = 0; j < 4; ++j) kw[j] = (bf16_t)kra[j];
            *reinterpret_cast<bf16x4*>(&Kl[cur ^ 1][kidx]) = kw;
            bf16x4 vw;
            #pragma unroll
            for (int j = 0; j < 4; ++j) vw[j] = (bf16_t)vv[j];
            *reinterpret_cast<bf16x4*>(&Vl[cur ^ 1][vidx]) = vw;
        }

        // ==== QK for both subtiles (two independent MFMA chains) ====
        f32x16 acc0, acc1;
        #pragma unroll
        for (int r = 0; r < 16; ++r) { acc0[r] = 0.f; acc1[r] = 0.f; }
        #pragma unroll
        for (int ks = 0; ks < 4; ++ks) {
            const uint32_t i0 = ((uint32_t)((l31) * Dk + ks * 16 + hi * 8)) ^ swz;
            bf16x8 af0 = *reinterpret_cast<const bf16x8*>(&Kl[cur][i0]);
            acc0 = __builtin_amdgcn_mfma_f32_32x32x16_bf16(af0, qf[ks], acc0, 0, 0, 0);
        }
        #pragma unroll
        for (int ks = 0; ks < 4; ++ks) {
            const uint32_t i1 = ((uint32_t)((32 + l31) * Dk + ks * 16 + hi * 8)) ^ swz;
            bf16x8 af1 = *reinterpret_cast<const bf16x8*>(&Kl[cur][i1]);
            acc1 = __builtin_amdgcn_mfma_f32_32x32x16_bf16(af1, qf[ks], acc1, 0, 0, 0);
        }

        // ---- mid-window: issue loads for tile t+2 (consumed at top of t+1;
        //      flight spans the rest of this window + the barrier) ----
        if (t + 2 < NIT) {
            kg  += (size_t)KVB * STRIDE_T;
            vgp += (size_t)KVB * STRIDE_T;
            kra = *reinterpret_cast<const f32x4*>(kg);
            #pragma unroll
            for (int j = 0; j < 4; ++j) vv[j] = vgp[(size_t)j * STRIDE_T];
        }

        // ---- SM(s0) ----
        bf16x8 pa00, pa01;
        {
            float p[16];
            #pragma unroll
            for (int r = 0; r < 16; ++r) p[r] = __builtin_exp2f(acc0[r]);
            l_acc += (((p[0]+p[1])+(p[2]+p[3]))+((p[4]+p[5])+(p[6]+p[7])))
                   + (((p[8]+p[9])+(p[10]+p[11]))+((p[12]+p[13])+(p[14]+p[15])));
            #pragma unroll
            for (int j = 0; j < 8; ++j) { pa00[j] = (bf16_t)p[j]; pa01[j] = (bf16_t)p[8+j]; }
        }

        // ---- PV(s0): cols 0..31 of V^T ----
        #pragma unroll
        for (int ks2 = 0; ks2 < 2; ++ks2) {
            bf16x8 pa = ks2 ? pa01 : pa00;
            const uint32_t colb = (uint32_t)(ks2 * 16 + hi * 8);
            const uint32_t i0 = ((uint32_t)(l31 * KVB) + colb) ^ swz;
            bf16x8 vf0 = *reinterpret_cast<const bf16x8*>(&Vl[cur][i0]);
            o0 = __builtin_amdgcn_mfma_f32_32x32x16_bf16(vf0, pa, o0, 0, 0, 0);
            const uint32_t i1 = ((uint32_t)((32 + l31) * KVB) + colb) ^ swz;
            bf16x8 vf1 = *reinterpret_cast<const bf16x8*>(&Vl[cur][i1]);
            o1 = __builtin_amdgcn_mfma_f32_32x32x16_bf16(vf1, pa, o1, 0, 0, 0);
        }

        // ---- SM(s1) (interleaves with PV(s0) MFMAs) ----
        bf16x8 pa10, pa11;
        {
            float p[16];
            #pragma unroll
            for (int r = 0; r < 16; ++r) p[r] = __builtin_exp2f(acc1[r]);
            l_acc += (((p[0]+p[1])+(p[2]+p[3]))+((p[4]+p[5])+(p[6]+p[7])))
                   + (((p[8]+p[9])+(p[10]+p[11]))+((p[12]+p[13])+(p[14]+p[15])));
            #pragma unroll
            for (int j = 0; j < 8; ++j) { pa10[j] = (bf16_t)p[j]; pa11[j] = (bf16_t)p[8+j]; }
        }

        // ---- PV(s1): cols 32..63 of V^T ----
        #pragma unroll
        for (int ks2 = 0; ks2 < 2; ++ks2) {
            bf16x8 pa = ks2 ? pa11 : pa10;
            const uint32_t colb = (uint32_t)(32 + ks2 * 16 + hi * 8);
            const uint32_t i0 = ((uint32_t)(l31 * KVB) + colb) ^ swz;
            bf16x8 vf0 = *reinterpret_cast<const bf16x8*>(&Vl[cur][i0]);
            o0 = __builtin_amdgcn_mfma_f32_32x32x16_bf16(vf0, pa, o0, 0, 0, 0);
            const uint32_t i1 = ((uint32_t)((32 + l31) * KVB) + colb) ^ swz;
            bf16x8 vf1 = *reinterpret_cast<const bf16x8*>(&Vl[cur][i1]);
            o1 = __builtin_amdgcn_mfma_f32_32x32x16_bf16(vf1, pa, o1, 0, 0, 0);
        }

        // ---- barrier: LDS complete per wave; global loads stay in flight ----
        lds_barrier();
    }

    // ---- epilogue: merge l halves, normalize, store ----
    float l_tot = l_acc + __shfl_xor(l_acc, 32, 64);
    const float inv = 1.0f / l_tot;
    float* ob = Ob + (size_t)(qt * QB + warp * 32 + l31) * STRIDE_T;
    #pragma unroll
    for (int r = 0; r < 16; ++r) {
        const int d = (r & 3) + 8 * (r >> 2) + 4 * hi;
        ob[d]      = o0[r] * inv;
        ob[d + 32] = o1[r] * inv;
    }
}

extern "C" void kernel_launch(void* const* d_in, const int* in_sizes, int n_in,
                              void* d_out, int out_size, void* d_ws, size_t ws_size,
                              hipStream_t stream) {
    const float* Q = (const float*)d_in[0];
    const float* K = (const float*)d_in[1];
    const float* V = (const float*)d_in[2];
    // d_in[3] = attention_mask (bool) — unused (mask_flag=False)
    float* O = (float*)d_out;

    const int nblocks = Bsz * Hn * (Tsz / QB);   // 256
    fattn<<<nblocks, 1024, 0, stream>>>(Q, K, V, O);
}

// Round 19
// 60.198 us; speedup vs baseline: 1.1089x; 1.1089x over previous
//
#include <hip/hip_runtime.h>
#include <hip/hip_bf16.h>
#include <stdint.h>

typedef __bf16 bf16_t;
typedef bf16_t bf16x8 __attribute__((ext_vector_type(8)));
typedef bf16_t bf16x4 __attribute__((ext_vector_type(4)));
typedef float  f32x4  __attribute__((ext_vector_type(4)));
typedef float  f32x16 __attribute__((ext_vector_type(16)));

constexpr int Bsz = 16, Tsz = 1024, Hn = 8, Dk = 64;
constexpr int QB  = 512;                 // q rows per block (16 warps x 32)
constexpr int KVB = 64;                  // kv rows per window
constexpr int NIT = Tsz / KVB;           // 16
constexpr int STRIDE_T = Hn * Dk;        // 512 floats between consecutive t
constexpr float QSCALE = 0.125f * 1.44269504f;   // 1/sqrt(64) * log2(e)

__global__ __launch_bounds__(1024, 4)
void fattn(const float* __restrict__ Q, const float* __restrict__ K,
           const float* __restrict__ V, float* __restrict__ O)
{
    // ---- bijective XCD-aware swizzle: 256 wgs, 8 XCDs, 32 contiguous per XCD ----
    const int orig = blockIdx.x;
    const int wg   = (orig & 7) * 32 + (orig >> 3);
    const int qt   = wg & 1;              // 2 q-blocks per head, adjacent -> same XCD
    const int bh   = wg >> 1;
    const int h    = bh & (Hn - 1);
    const int b    = bh >> 3;

    const int tid  = threadIdx.x;
    const int warp = tid >> 6;            // 0..15
    const int lane = tid & 63;
    const int l31  = lane & 31;
    const int hi   = lane >> 5;           // 0/1

    // double-buffered tiles (32 KB total)
    __shared__ alignas(16) bf16_t Kl[2][KVB * Dk];   // [kv][e], XOR-swizzled rows
    __shared__ alignas(16) bf16_t Vl[2][Dk * KVB];   // V^T: [d][pos], pos = swap23(kv), XOR-swizzled

    const size_t base = (size_t)b * (Tsz * Hn * Dk) + (size_t)h * Dk;
    const float* Qb = Q + base;
    const float* Kb = K + base;
    const float* Vb = V + base;
    float*       Ob = O + base;

    // ---- Q fragments (B operand of swapped QK^T), scale*log2e folded ----
    bf16x8 qf[4];
    {
        const float* qs = Qb + (size_t)(qt * QB + warp * 32 + l31) * STRIDE_T + hi * 8;
        #pragma unroll
        for (int ks = 0; ks < 4; ++ks) {
            f32x4 lo = *reinterpret_cast<const f32x4*>(qs + ks * 16);
            f32x4 hh = *reinterpret_cast<const f32x4*>(qs + ks * 16 + 4);
            bf16x8 f;
            #pragma unroll
            for (int j = 0; j < 4; ++j) {
                f[j]     = (bf16_t)(lo[j] * QSCALE);
                f[4 + j] = (bf16_t)(hh[j] * QSCALE);
            }
            qf[ks] = f;
        }
    }

    // ---- staging assignments (1024 threads; 4 elems each for K and V) ----
    const int kr  = tid >> 4;             // 0..63
    const int ke0 = (tid & 15) * 4;       // 0..60
    const float* kg = Kb + (size_t)kr * STRIDE_T + ke0;
    const uint32_t kidx = (uint32_t)(kr * Dk + ke0) ^ (uint32_t)((kr & 7) << 3);

    const int vd   = tid & 63;
    const int pos0 = (tid >> 6) * 4;      // 0..60 (multiple of 4)
    const int vs0  = (pos0 & ~12) | ((pos0 & 4) << 1) | ((pos0 & 8) >> 1);   // swap23
    const float* vgp = Vb + (size_t)vs0 * STRIDE_T + vd;
    const uint32_t vidx = (uint32_t)(vd * KVB + pos0) ^ (uint32_t)((vd & 7) << 3);

    const uint32_t swz = (uint32_t)((l31 & 7) << 3);

    // ---- accumulators; l per-lane-half, merged in epilogue ----
    f32x16 o0, o1;
    #pragma unroll
    for (int r = 0; r < 16; ++r) { o0[r] = 0.f; o1[r] = 0.f; }
    float l_acc = 0.f;

    // ---- prologue: tile 0 -> regs -> buf0 ----
    f32x4 kra;
    float vv[4];
    kra = *reinterpret_cast<const f32x4*>(kg);
    #pragma unroll
    for (int j = 0; j < 4; ++j) vv[j] = vgp[(size_t)j * STRIDE_T];
    {
        bf16x4 kw;
        #pragma unroll
        for (int j = 0; j < 4; ++j) kw[j] = (bf16_t)kra[j];
        *reinterpret_cast<bf16x4*>(&Kl[0][kidx]) = kw;
        bf16x4 vw;
        #pragma unroll
        for (int j = 0; j < 4; ++j) vw[j] = (bf16_t)vv[j];
        *reinterpret_cast<bf16x4*>(&Vl[0][vidx]) = vw;
    }
    __syncthreads();

    for (int t = 0; t < NIT; ++t) {
        const int cur = t & 1;

        // ---- issue prefetch of tile t+1 (written to other buffer at window tail) ----
        if (t + 1 < NIT) {
            kg  += (size_t)KVB * STRIDE_T;
            vgp += (size_t)KVB * STRIDE_T;
            kra = *reinterpret_cast<const f32x4*>(kg);
            #pragma unroll
            for (int j = 0; j < 4; ++j) vv[j] = vgp[(size_t)j * STRIDE_T];
        }

        // ==== window body: both subtiles, structured for cross-phase ILP ====
        // QK for BOTH subtiles first (two independent MFMA chains), then
        // SM(s0) / PV(s0) / SM(s1) / PV(s1) — no setprio fences, so the
        // scheduler interleaves QK(s1) with SM(s0) and SM(s1) with PV(s0).

        f32x16 acc0, acc1;
        #pragma unroll
        for (int r = 0; r < 16; ++r) { acc0[r] = 0.f; acc1[r] = 0.f; }
        #pragma unroll
        for (int ks = 0; ks < 4; ++ks) {
            const uint32_t i0 = ((uint32_t)((l31) * Dk + ks * 16 + hi * 8)) ^ swz;
            bf16x8 af0 = *reinterpret_cast<const bf16x8*>(&Kl[cur][i0]);
            acc0 = __builtin_amdgcn_mfma_f32_32x32x16_bf16(af0, qf[ks], acc0, 0, 0, 0);
        }
        #pragma unroll
        for (int ks = 0; ks < 4; ++ks) {
            const uint32_t i1 = ((uint32_t)((32 + l31) * Dk + ks * 16 + hi * 8)) ^ swz;
            bf16x8 af1 = *reinterpret_cast<const bf16x8*>(&Kl[cur][i1]);
            acc1 = __builtin_amdgcn_mfma_f32_32x32x16_bf16(af1, qf[ks], acc1, 0, 0, 0);
        }

        // ---- SM(s0) ----
        bf16x8 pa00, pa01;
        {
            float p[16];
            #pragma unroll
            for (int r = 0; r < 16; ++r) p[r] = __builtin_exp2f(acc0[r]);
            l_acc += (((p[0]+p[1])+(p[2]+p[3]))+((p[4]+p[5])+(p[6]+p[7])))
                   + (((p[8]+p[9])+(p[10]+p[11]))+((p[12]+p[13])+(p[14]+p[15])));
            #pragma unroll
            for (int j = 0; j < 8; ++j) { pa00[j] = (bf16_t)p[j]; pa01[j] = (bf16_t)p[8+j]; }
        }

        // ---- PV(s0): cols 0..31 of V^T ----
        #pragma unroll
        for (int ks2 = 0; ks2 < 2; ++ks2) {
            bf16x8 pa = ks2 ? pa01 : pa00;
            const uint32_t colb = (uint32_t)(ks2 * 16 + hi * 8);
            const uint32_t i0 = ((uint32_t)(l31 * KVB) + colb) ^ swz;
            bf16x8 vf0 = *reinterpret_cast<const bf16x8*>(&Vl[cur][i0]);
            o0 = __builtin_amdgcn_mfma_f32_32x32x16_bf16(vf0, pa, o0, 0, 0, 0);
            const uint32_t i1 = ((uint32_t)((32 + l31) * KVB) + colb) ^ swz;
            bf16x8 vf1 = *reinterpret_cast<const bf16x8*>(&Vl[cur][i1]);
            o1 = __builtin_amdgcn_mfma_f32_32x32x16_bf16(vf1, pa, o1, 0, 0, 0);
        }

        // ---- SM(s1) (scheduler interleaves with PV(s0) MFMAs) ----
        bf16x8 pa10, pa11;
        {
            float p[16];
            #pragma unroll
            for (int r = 0; r < 16; ++r) p[r] = __builtin_exp2f(acc1[r]);
            l_acc += (((p[0]+p[1])+(p[2]+p[3]))+((p[4]+p[5])+(p[6]+p[7])))
                   + (((p[8]+p[9])+(p[10]+p[11]))+((p[12]+p[13])+(p[14]+p[15])));
            #pragma unroll
            for (int j = 0; j < 8; ++j) { pa10[j] = (bf16_t)p[j]; pa11[j] = (bf16_t)p[8+j]; }
        }

        // ---- PV(s1): cols 32..63 of V^T ----
        #pragma unroll
        for (int ks2 = 0; ks2 < 2; ++ks2) {
            bf16x8 pa = ks2 ? pa11 : pa10;
            const uint32_t colb = (uint32_t)(32 + ks2 * 16 + hi * 8);
            const uint32_t i0 = ((uint32_t)(l31 * KVB) + colb) ^ swz;
            bf16x8 vf0 = *reinterpret_cast<const bf16x8*>(&Vl[cur][i0]);
            o0 = __builtin_amdgcn_mfma_f32_32x32x16_bf16(vf0, pa, o0, 0, 0, 0);
            const uint32_t i1 = ((uint32_t)((32 + l31) * KVB) + colb) ^ swz;
            bf16x8 vf1 = *reinterpret_cast<const bf16x8*>(&Vl[cur][i1]);
            o1 = __builtin_amdgcn_mfma_f32_32x32x16_bf16(vf1, pa, o1, 0, 0, 0);
        }

        // ---- window tail: write tile t+1 regs -> other buffer ----
        if (t + 1 < NIT) {
            bf16x4 kw;
            #pragma unroll
            for (int j = 0; j < 4; ++j) kw[j] = (bf16_t)kra[j];
            *reinterpret_cast<bf16x4*>(&Kl[cur ^ 1][kidx]) = kw;
            bf16x4 vw;
            #pragma unroll
            for (int j = 0; j < 4; ++j) vw[j] = (bf16_t)vv[j];
            *reinterpret_cast<bf16x4*>(&Vl[cur ^ 1][vidx]) = vw;
        }
        __syncthreads();
    }

    // ---- epilogue: merge l halves, normalize, store ----
    float l_tot = l_acc + __shfl_xor(l_acc, 32, 64);
    const float inv = 1.0f / l_tot;
    float* ob = Ob + (size_t)(qt * QB + warp * 32 + l31) * STRIDE_T;
    #pragma unroll
    for (int r = 0; r < 16; ++r) {
        const int d = (r & 3) + 8 * (r >> 2) + 4 * hi;
        ob[d]      = o0[r] * inv;
        ob[d + 32] = o1[r] * inv;
    }
}

extern "C" void kernel_launch(void* const* d_in, const int* in_sizes, int n_in,
                              void* d_out, int out_size, void* d_ws, size_t ws_size,
                              hipStream_t stream) {
    const float* Q = (const float*)d_in[0];
    const float* K = (const float*)d_in[1];
    const float* V = (const float*)d_in[2];
    // d_in[3] = attention_mask (bool) — unused (mask_flag=False)
    float* O = (float*)d_out;

    const int nblocks = Bsz * Hn * (Tsz / QB);   // 256
    fattn<<<nblocks, 1024, 0, stream>>>(Q, K, V, O);
}